// Round 1
// baseline (748.120 us; speedup 1.0000x reference)
//
#include <hip/hip_runtime.h>
#include <hip/hip_bf16.h>

#define BATCH 64
#define UNITS 1024

// ---------------- transpose x[64][nfeat] f32 -> xT[nfeat][64] bf16 ----------------
__global__ __launch_bounds__(256)
void transpose_x_kernel(const float* __restrict__ x, __hip_bfloat16* __restrict__ xT,
                        int nfeat) {
    __shared__ float tile[64][65];          // +1 pad: conflict-free transpose
    const int c0 = blockIdx.x * 64;
    const int tx = threadIdx.x;             // 0..63
    const int ty = threadIdx.y;             // 0..3
    for (int b = ty; b < 64; b += 4) {
        int col = c0 + tx;
        if (col < nfeat) tile[b][tx] = x[(size_t)b * nfeat + col];  // coalesced 256B
    }
    __syncthreads();
    for (int i = ty; i < 64; i += 4) {
        int col = c0 + i;
        if (col < nfeat)
            xT[(size_t)col * 64 + tx] = __float2bfloat16(tile[tx][i]);  // coalesced 128B
    }
}

// ---------------- main scatter: LDS-privatized accumulation ----------------
// Grid = 256 WGs (1/CU). bid&1 selects batch-half (32 batches), bid>>1 selects
// the nnz chunk. priv layout [c*32 + b_local] -> half-wave scatter hits 32
// distinct banks (conflict-free LDS atomics).
template<bool USE_SCRATCH>
__global__ __launch_bounds__(1024, 1)
void scatter_kernel(const __hip_bfloat16* __restrict__ xT,
                    const float* __restrict__ w,
                    const int* __restrict__ row_idx,
                    const int* __restrict__ col_idx,
                    float* __restrict__ out,
                    float* __restrict__ copies,
                    int nnz) {
    extern __shared__ float priv[];         // 32 * 1024 f32 = 128 KiB
    const int tid = threadIdx.x;
    for (int i = tid; i < 32 * UNITS; i += 1024) priv[i] = 0.0f;
    __syncthreads();

    const int bid   = blockIdx.x;           // 0..255
    const int half  = bid & 1;
    const int wgIdx = bid >> 1;             // 0..127
    const int wave  = tid >> 6;             // 0..15
    const int lane  = tid & 63;
    const int h     = lane >> 5;            // which k of the pair
    const int bl    = lane & 31;            // local batch 0..31

    const int per  = (nnz + 127) >> 7;      // ceil(nnz/128) = 15625
    const int k0   = wgIdx * per;
    const int kend = min(k0 + per, nnz);
    const __hip_bfloat16* xTh = xT + half * 32 + bl;

    for (int k = k0 + wave * 2 + h; k < kend; k += 32) {
        const int   r  = row_idx[k];        // broadcast across half-wave
        const int   c  = col_idx[k];
        const float wv = w[k];
        const float xv = __bfloat162float(xTh[(size_t)r * 64]);  // coalesced 64B/half-wave
        atomicAdd(&priv[c * 32 + bl], xv * wv);
    }
    __syncthreads();

    if (USE_SCRATCH) {
        float* dst = copies + (size_t)bid * (32 * UNITS);
        for (int i = tid; i < 32 * UNITS; i += 1024) dst[i] = priv[i];  // coalesced
    } else {
        for (int i = tid; i < 32 * UNITS; i += 1024) {
            int c = i >> 5;
            int b = half * 32 + (i & 31);
            unsafeAtomicAdd(&out[b * UNITS + c], priv[i]);
        }
    }
}

// ---------------- merge the 256 private copies (no atomics) ----------------
__global__ __launch_bounds__(256)
void reduce_copies_kernel(const float* __restrict__ copies, float* __restrict__ out) {
    const int gid  = blockIdx.x * 256 + threadIdx.x;   // 0..65535
    const int half = gid >> 15;
    const int idx  = gid & 32767;                      // c*32 + b_local
    float s = 0.0f;
#pragma unroll 4
    for (int wg = 0; wg < 128; ++wg)
        s += copies[(size_t)(wg * 2 + half) * (32 * UNITS) + idx];  // coalesced
    const int b = half * 32 + (idx & 31);
    const int c = idx >> 5;
    out[b * UNITS + c] = s;                            // every out cell written once
}

// ---------------- fallback if ws is tiny: direct global atomics ----------------
__global__ __launch_bounds__(256)
void fallback_kernel(const float* __restrict__ x, const float* __restrict__ w,
                     const int* __restrict__ row_idx, const int* __restrict__ col_idx,
                     float* __restrict__ out, int nnz, int nfeat) {
    const int nwaves = (gridDim.x * blockDim.x) >> 6;
    const int wid    = (blockIdx.x * blockDim.x + threadIdx.x) >> 6;
    const int lane   = threadIdx.x & 63;    // lane = batch
    for (int k = wid; k < nnz; k += nwaves) {
        const int   r = row_idx[k];
        const int   c = col_idx[k];
        const float v = x[(size_t)lane * nfeat + r] * w[k];
        unsafeAtomicAdd(&out[lane * UNITS + c], v);
    }
}

extern "C" void kernel_launch(void* const* d_in, const int* in_sizes, int n_in,
                              void* d_out, int out_size, void* d_ws, size_t ws_size,
                              hipStream_t stream) {
    const float* x       = (const float*)d_in[0];
    const float* w       = (const float*)d_in[1];
    const int*   row_idx = (const int*)d_in[2];
    const int*   col_idx = (const int*)d_in[3];
    float*       out     = (float*)d_out;
    const int    nnz     = in_sizes[1];
    const int    nfeat   = in_sizes[0] / BATCH;

    const size_t xT_bytes     = (size_t)nfeat * 64 * sizeof(__hip_bfloat16);  // 6.4 MB
    const size_t copies_off   = (xT_bytes + 255) & ~(size_t)255;
    const size_t copies_bytes = (size_t)256 * 32 * UNITS * sizeof(float);     // 33.5 MB

    if (ws_size >= copies_off + copies_bytes) {
        // Path A: transpose -> LDS scatter -> scratch copies -> reduction (no global atomics)
        __hip_bfloat16* xT = (__hip_bfloat16*)d_ws;
        float* copies = (float*)((char*)d_ws + copies_off);
        dim3 tb(64, 4);
        transpose_x_kernel<<<(nfeat + 63) / 64, tb, 0, stream>>>(x, xT, nfeat);
        scatter_kernel<true><<<256, 1024, 32 * UNITS * sizeof(float), stream>>>(
            xT, w, row_idx, col_idx, out, copies, nnz);
        reduce_copies_kernel<<<(BATCH * UNITS) / 256, 256, 0, stream>>>(copies, out);
    } else if (ws_size >= xT_bytes) {
        // Path B: same but merge via global atomics
        __hip_bfloat16* xT = (__hip_bfloat16*)d_ws;
        hipMemsetAsync(d_out, 0, (size_t)out_size * sizeof(float), stream);
        dim3 tb(64, 4);
        transpose_x_kernel<<<(nfeat + 63) / 64, tb, 0, stream>>>(x, xT, nfeat);
        scatter_kernel<false><<<256, 1024, 32 * UNITS * sizeof(float), stream>>>(
            xT, w, row_idx, col_idx, out, nullptr, nnz);
    } else {
        // Path C: no workspace — direct global atomic scatter
        hipMemsetAsync(d_out, 0, (size_t)out_size * sizeof(float), stream);
        fallback_kernel<<<2048, 256, 0, stream>>>(x, w, row_idx, col_idx, out, nnz, nfeat);
    }
}

// Round 3
// 735.400 us; speedup vs baseline: 1.0173x; 1.0173x over previous
//
#include <hip/hip_runtime.h>
#include <hip/hip_bf16.h>

#define BATCH 64
#define UNITS 1024

// ---------------- transpose x[64][nfeat] f32 -> xT[nfeat][64] bf16 ----------------
__global__ __launch_bounds__(256)
void transpose_x_kernel(const float* __restrict__ x, __hip_bfloat16* __restrict__ xT,
                        int nfeat) {
    __shared__ float tile[64][65];          // +1 pad: conflict-free transpose
    const int c0 = blockIdx.x * 64;
    const int tx = threadIdx.x;             // 0..63
    const int ty = threadIdx.y;             // 0..3
    for (int b = ty; b < 64; b += 4) {
        int col = c0 + tx;
        if (col < nfeat) tile[b][tx] = x[(size_t)b * nfeat + col];  // coalesced 256B
    }
    __syncthreads();
    for (int i = ty; i < 64; i += 4) {
        int col = c0 + i;
        if (col < nfeat)
            xT[(size_t)col * 64 + tx] = __float2bfloat16(tile[tx][i]);  // coalesced 128B
    }
}

// ---------------- main scatter: LDS-privatized accumulation ----------------
// Grid = 256 WGs (1/CU). half = bid>>7 so WGs (c, c+128) share a k-chunk AND
// land on the same XCD (round-robin %8; 128%8==0) -> index streams hit L2 once.
// priv layout [c*32 + b_local]: half-wave scatter hits 32 distinct banks.
// U=8 manual unroll: 8 independent gathers in flight per wave (the round-1
// kernel had VGPR=8 and a fully serialized load->use chain, 3300 cy/iter).
template<bool USE_SCRATCH>
__global__ __launch_bounds__(1024, 1)
void scatter_kernel(const __hip_bfloat16* __restrict__ xT,
                    const float* __restrict__ w,
                    const int* __restrict__ row_idx,
                    const int* __restrict__ col_idx,
                    float* __restrict__ out,
                    float* __restrict__ copies,
                    int nnz) {
    extern __shared__ float priv[];         // 32 * 1024 f32 = 128 KiB
    const int tid = threadIdx.x;
    for (int i = tid; i < 32 * UNITS; i += 1024) priv[i] = 0.0f;
    __syncthreads();

    const int bid   = blockIdx.x;           // 0..255
    const int half  = bid >> 7;             // 0..1  (batch half)
    const int wgIdx = bid & 127;            // 0..127 (k-chunk)
    const int wave  = tid >> 6;             // 0..15
    const int lane  = tid & 63;
    const int h     = lane >> 5;            // which k of the wave's pair
    const int bl    = lane & 31;            // local batch 0..31

    const int per  = (nnz + 127) >> 7;      // ceil(nnz/128) = 15625
    const int k0   = wgIdx * per;
    const int kend = min(k0 + per, nnz);
    const __hip_bfloat16* xTh = xT + half * 32 + bl;

    constexpr int U = 8;
    int k = k0 + wave * 2 + h;
    // main unrolled loop: batch the index loads, then the gathers, then the
    // FMA+LDS-atomic drains -> 8 outstanding gathers per wave.
    for (; k + 32 * (U - 1) < kend; k += 32 * U) {
        int rr[U], cc[U];
        float wv[U];
#pragma unroll
        for (int u = 0; u < U; ++u) {
            rr[u] = row_idx[k + 32 * u];
            cc[u] = col_idx[k + 32 * u];
            wv[u] = w[k + 32 * u];
        }
        float xv[U];
#pragma unroll
        for (int u = 0; u < U; ++u)
            xv[u] = __bfloat162float(xTh[(size_t)rr[u] * 64]);  // 64B/half-wave, random row
#pragma unroll
        for (int u = 0; u < U; ++u)
            atomicAdd(&priv[cc[u] * 32 + bl], xv[u] * wv[u]);   // ds_add_f32, conflict-free
    }
    // tail
    for (; k < kend; k += 32) {
        const int   r  = row_idx[k];
        const int   c  = col_idx[k];
        const float wvs = w[k];
        atomicAdd(&priv[c * 32 + bl], __bfloat162float(xTh[(size_t)r * 64]) * wvs);
    }
    __syncthreads();

    if (USE_SCRATCH) {
        float* dst = copies + (size_t)bid * (32 * UNITS);
        for (int i = tid; i < 32 * UNITS; i += 1024) dst[i] = priv[i];  // coalesced
    } else {
        for (int i = tid; i < 32 * UNITS; i += 1024) {
            int c = i >> 5;
            int b = half * 32 + (i & 31);
            unsafeAtomicAdd(&out[b * UNITS + c], priv[i]);
        }
    }
}

// ---------------- merge the 256 private copies (no atomics) ----------------
// copies[bid] with bid = half*128 + wg  (must match scatter's bid mapping)
__global__ __launch_bounds__(256)
void reduce_copies_kernel(const float* __restrict__ copies, float* __restrict__ out) {
    const int gid  = blockIdx.x * 256 + threadIdx.x;   // 0..65535
    const int half = gid >> 15;
    const int idx  = gid & 32767;                      // c*32 + b_local
    float s = 0.0f;
#pragma unroll 4
    for (int wg = 0; wg < 128; ++wg)
        s += copies[(size_t)(half * 128 + wg) * (32 * UNITS) + idx];  // coalesced
    const int b = half * 32 + (idx & 31);
    const int c = idx >> 5;
    out[b * UNITS + c] = s;                            // every out cell written once
}

// ---------------- fallback if ws is tiny: direct global atomics ----------------
__global__ __launch_bounds__(256)
void fallback_kernel(const float* __restrict__ x, const float* __restrict__ w,
                     const int* __restrict__ row_idx, const int* __restrict__ col_idx,
                     float* __restrict__ out, int nnz, int nfeat) {
    const int nwaves = (gridDim.x * blockDim.x) >> 6;
    const int wid    = (blockIdx.x * blockDim.x + threadIdx.x) >> 6;
    const int lane   = threadIdx.x & 63;    // lane = batch
    for (int k = wid; k < nnz; k += nwaves) {
        const int   r = row_idx[k];
        const int   c = col_idx[k];
        const float v = x[(size_t)lane * nfeat + r] * w[k];
        unsafeAtomicAdd(&out[lane * UNITS + c], v);
    }
}

extern "C" void kernel_launch(void* const* d_in, const int* in_sizes, int n_in,
                              void* d_out, int out_size, void* d_ws, size_t ws_size,
                              hipStream_t stream) {
    const float* x       = (const float*)d_in[0];
    const float* w       = (const float*)d_in[1];
    const int*   row_idx = (const int*)d_in[2];
    const int*   col_idx = (const int*)d_in[3];
    float*       out     = (float*)d_out;
    const int    nnz     = in_sizes[1];
    const int    nfeat   = in_sizes[0] / BATCH;

    const size_t xT_bytes     = (size_t)nfeat * 64 * sizeof(__hip_bfloat16);  // 6.4 MB
    const size_t copies_off   = (xT_bytes + 255) & ~(size_t)255;
    const size_t copies_bytes = (size_t)256 * 32 * UNITS * sizeof(float);     // 33.5 MB

    if (ws_size >= copies_off + copies_bytes) {
        // Path A: transpose -> LDS scatter -> scratch copies -> reduction (no global atomics)
        __hip_bfloat16* xT = (__hip_bfloat16*)d_ws;
        float* copies = (float*)((char*)d_ws + copies_off);
        dim3 tb(64, 4);
        transpose_x_kernel<<<(nfeat + 63) / 64, tb, 0, stream>>>(x, xT, nfeat);
        scatter_kernel<true><<<256, 1024, 32 * UNITS * sizeof(float), stream>>>(
            xT, w, row_idx, col_idx, out, copies, nnz);
        reduce_copies_kernel<<<(BATCH * UNITS) / 256, 256, 0, stream>>>(copies, out);
    } else if (ws_size >= xT_bytes) {
        // Path B: same but merge via global atomics
        __hip_bfloat16* xT = (__hip_bfloat16*)d_ws;
        hipMemsetAsync(d_out, 0, (size_t)out_size * sizeof(float), stream);
        dim3 tb(64, 4);
        transpose_x_kernel<<<(nfeat + 63) / 64, tb, 0, stream>>>(x, xT, nfeat);
        scatter_kernel<false><<<256, 1024, 32 * UNITS * sizeof(float), stream>>>(
            xT, w, row_idx, col_idx, out, nullptr, nnz);
    } else {
        // Path C: no workspace — direct global atomic scatter
        hipMemsetAsync(d_out, 0, (size_t)out_size * sizeof(float), stream);
        fallback_kernel<<<2048, 256, 0, stream>>>(x, w, row_idx, col_idx, out, nnz, nfeat);
    }
}

// Round 5
// 199.074 us; speedup vs baseline: 3.7580x; 3.6941x over previous
//
#include <hip/hip_runtime.h>
#include <hip/hip_bf16.h>

#define BATCH 64
#define UNITS 1024

typedef unsigned int u32;
typedef unsigned short u16;

// ---------------- zero a uint4-aligned region (graph-safe, no memset) ------
__global__ __launch_bounds__(256)
void zero4_kernel(uint4* __restrict__ p, int n4) {
    int i = blockIdx.x * 256 + threadIdx.x;
    const int stride = gridDim.x * 256;
    const uint4 z = make_uint4(0u, 0u, 0u, 0u);
    for (; i < n4; i += stride) p[i] = z;
}

// ---------------- transpose x[64][nfeat] f32 -> xT[nfeat][64] bf16 ---------
__global__ __launch_bounds__(256)
void transpose_x_kernel(const float* __restrict__ x, u16* __restrict__ xT,
                        int nfeat) {
    __shared__ float tile[64][65];
    const int c0 = blockIdx.x * 64;
    const int tx = threadIdx.x;             // 0..63
    const int ty = threadIdx.y;             // 0..3
    for (int b = ty; b < 64; b += 4) {
        int col = c0 + tx;
        if (col < nfeat) tile[b][tx] = x[(size_t)b * nfeat + col];
    }
    __syncthreads();
    for (int i = ty; i < 64; i += 4) {
        int col = c0 + i;
        if (col < nfeat) {
            // f32 -> bf16 bits (round-to-nearest-even via __float2bfloat16)
            __hip_bfloat16 h = __float2bfloat16(tile[tx][i]);
            xT[(size_t)col * 64 + tx] = *(u16*)&h;
        }
    }
}

// ---------------- pass 1: per-column histogram -----------------------------
__global__ __launch_bounds__(256)
void hist_kernel(const int* __restrict__ col, u32* __restrict__ ghist, int nnz) {
    __shared__ u32 lh[UNITS];
    for (int i = threadIdx.x; i < UNITS; i += 256) lh[i] = 0u;
    __syncthreads();
    const int stride = gridDim.x * 256;
    for (int k = blockIdx.x * 256 + threadIdx.x; k < nnz; k += stride)
        atomicAdd(&lh[col[k]], 1u);
    __syncthreads();
    for (int i = threadIdx.x; i < UNITS; i += 256)
        if (lh[i]) atomicAdd(&ghist[i], lh[i]);
}

// ---------------- pass 2: exclusive scan of 64-padded counts ---------------
// Pads each column's bin to a multiple of 64 so the gather loop has no tail;
// pad slots stay zero (w=0) from the zero4 pass.
__global__ __launch_bounds__(1024)
void scan_kernel(const u32* __restrict__ ghist, u32* __restrict__ col_start,
                 u32* __restrict__ cursor) {
    __shared__ u32 a[UNITS];
    const int tid = threadIdx.x;
    const u32 cp = (ghist[tid] + 63u) & ~63u;
    a[tid] = cp;
    __syncthreads();
    for (int off = 1; off < UNITS; off <<= 1) {
        u32 add = (tid >= off) ? a[tid - off] : 0u;
        u32 v = a[tid];
        __syncthreads();
        a[tid] = v + add;
        __syncthreads();
    }
    const u32 incl = a[tid], excl = incl - cp;
    col_start[tid] = excl;
    cursor[tid] = excl;
    if (tid == UNITS - 1) col_start[UNITS] = incl;
}

// ---------------- pass 3: reorder (r,w) pairs into column bins -------------
// LDS-aggregated cursor reservation: one global atomic per (WG, column).
__global__ __launch_bounds__(256)
void reorder_kernel(const int* __restrict__ row, const int* __restrict__ col,
                    const float* __restrict__ w, u32* __restrict__ cursor,
                    uint2* __restrict__ sorted, int nnz) {
    __shared__ int carr[2048];
    __shared__ u32 lh[UNITS], base[UNITS], lc[UNITS];
    const int tid = threadIdx.x;
    const int g0 = blockIdx.x * 2048;
    const int n = min(2048, nnz - g0);
    for (int i = tid; i < UNITS; i += 256) { lh[i] = 0u; lc[i] = 0u; }
    __syncthreads();
    for (int i = tid; i < n; i += 256) {
        int c = col[g0 + i];
        carr[i] = c;
        atomicAdd(&lh[c], 1u);
    }
    __syncthreads();
    for (int c = tid; c < UNITS; c += 256)
        if (lh[c]) base[c] = atomicAdd(&cursor[c], lh[c]);
    __syncthreads();
    for (int i = tid; i < n; i += 256) {
        int c = carr[i];
        u32 lo = atomicAdd(&lc[c], 1u);
        sorted[base[c] + lo] = make_uint2((u32)row[g0 + i], __float_as_uint(w[g0 + i]));
    }
}

// ---------------- pass 4: per-column register-accumulated gather -----------
// WG = one column, lane = batch. Indices arrive via one coalesced uint2 load
// per 64 entries; (r,w) extracted with v_readlane (register-only, no dependent
// index loads). 8 independent gathers per unroll group, 8 accumulators.
__global__ __launch_bounds__(256)
void gather_kernel(const u16* __restrict__ xTu, const uint2* __restrict__ sorted,
                   const u32* __restrict__ col_start, float* __restrict__ outT) {
    const int u = blockIdx.x;
    const int wv = threadIdx.x >> 6;
    const int lane = threadIdx.x & 63;
    const u32 s = col_start[u], e = col_start[u + 1];
    float acc[8] = {0.f, 0.f, 0.f, 0.f, 0.f, 0.f, 0.f, 0.f};
    for (u32 b0 = s + (u32)wv * 64u; b0 < e; b0 += 256u) {
        const uint2 pk = sorted[b0 + lane];     // 64 entries, coalesced 512B
#pragma unroll
        for (int g = 0; g < 8; ++g) {
            int rr[8], wb[8];
#pragma unroll
            for (int j = 0; j < 8; ++j) {
                rr[j] = __builtin_amdgcn_readlane((int)pk.x, g * 8 + j);
                wb[j] = __builtin_amdgcn_readlane((int)pk.y, g * 8 + j);
            }
            float xv[8];
#pragma unroll
            for (int j = 0; j < 8; ++j) {
                const u16* p = xTu + ((size_t)(u32)rr[j] << 6);   // uniform base
                xv[j] = __uint_as_float(((u32)p[lane]) << 16);    // bf16 -> f32
            }
#pragma unroll
            for (int j = 0; j < 8; ++j)
                acc[j] = fmaf(xv[j], __uint_as_float((u32)wb[j]), acc[j]);
        }
    }
    float tot = ((acc[0] + acc[1]) + (acc[2] + acc[3])) +
                ((acc[4] + acc[5]) + (acc[6] + acc[7]));
    __shared__ float red[4][64];
    red[wv][lane] = tot;
    __syncthreads();
    if (wv == 0)
        outT[(size_t)u * 64 + lane] =
            red[0][lane] + red[1][lane] + red[2][lane] + red[3][lane];
}

// ---------------- pass 5: outT[1024][64] -> out[64][1024] ------------------
__global__ __launch_bounds__(256)
void transpose_out_kernel(const float* __restrict__ outT, float* __restrict__ out) {
    __shared__ float t[64][65];
    const int u0 = blockIdx.x * 64;
    const int tx = threadIdx.x, ty = threadIdx.y;
    for (int i = ty; i < 64; i += 4) t[i][tx] = outT[(size_t)(u0 + i) * 64 + tx];
    __syncthreads();
    for (int b = ty; b < 64; b += 4) out[(size_t)b * UNITS + u0 + tx] = t[tx][b];
}

// ---------------- small-ws fallbacks (kept from round 1; rarely used) ------
__global__ __launch_bounds__(1024, 1)
void scatter_fallback_kernel(const u16* __restrict__ xT, const float* __restrict__ w,
                             const int* __restrict__ row_idx, const int* __restrict__ col_idx,
                             float* __restrict__ out, int nnz) {
    extern __shared__ float priv[];
    const int tid = threadIdx.x;
    for (int i = tid; i < 32 * UNITS; i += 1024) priv[i] = 0.0f;
    __syncthreads();
    const int bid = blockIdx.x, half = bid >> 7, wgIdx = bid & 127;
    const int wave = tid >> 6, lane = tid & 63, h = lane >> 5, bl = lane & 31;
    const int per = (nnz + 127) >> 7;
    const int k0 = wgIdx * per, kend = min(k0 + per, nnz);
    const u16* xTh = xT + half * 32 + bl;
    for (int k = k0 + wave * 2 + h; k < kend; k += 32) {
        const int r = row_idx[k], c = col_idx[k];
        const float xv = __uint_as_float(((u32)xTh[(size_t)r * 64]) << 16);
        atomicAdd(&priv[c * 32 + bl], xv * w[k]);
    }
    __syncthreads();
    for (int i = tid; i < 32 * UNITS; i += 1024) {
        int c = i >> 5, b = half * 32 + (i & 31);
        unsafeAtomicAdd(&out[b * UNITS + c], priv[i]);
    }
}

__global__ __launch_bounds__(256)
void fallback_kernel(const float* __restrict__ x, const float* __restrict__ w,
                     const int* __restrict__ row_idx, const int* __restrict__ col_idx,
                     float* __restrict__ out, int nnz, int nfeat) {
    const int nwaves = (gridDim.x * blockDim.x) >> 6;
    const int wid = (blockIdx.x * blockDim.x + threadIdx.x) >> 6;
    const int lane = threadIdx.x & 63;
    for (int k = wid; k < nnz; k += nwaves) {
        const int r = row_idx[k], c = col_idx[k];
        unsafeAtomicAdd(&out[lane * UNITS + c], x[(size_t)lane * nfeat + r] * w[k]);
    }
}

static inline size_t align256(size_t v) { return (v + 255) & ~(size_t)255; }

extern "C" void kernel_launch(void* const* d_in, const int* in_sizes, int n_in,
                              void* d_out, int out_size, void* d_ws, size_t ws_size,
                              hipStream_t stream) {
    const float* x       = (const float*)d_in[0];
    const float* w       = (const float*)d_in[1];
    const int*   row_idx = (const int*)d_in[2];
    const int*   col_idx = (const int*)d_in[3];
    float*       out     = (float*)d_out;
    const int    nnz     = in_sizes[1];
    const int    nfeat   = in_sizes[0] / BATCH;

    // ws layout
    const size_t xT_off     = 0;
    const size_t xT_bytes   = (size_t)nfeat * 64 * sizeof(u16);           // 6.4 MB
    size_t o                = align256(xT_bytes);
    const size_t sorted_off = o;
    const size_t sorted_n   = (size_t)nnz + (size_t)UNITS * 64;           // + pad slots
    o = align256(o + sorted_n * sizeof(uint2));                           // ~16.5 MB
    const size_t ghist_off  = o;  o = align256(o + UNITS * sizeof(u32));
    const size_t cs_off     = o;  o = align256(o + (UNITS + 1) * sizeof(u32));
    const size_t cur_off    = o;  o = align256(o + UNITS * sizeof(u32));
    const size_t outT_off   = o;  o = align256(o + (size_t)UNITS * 64 * sizeof(float));

    if (ws_size >= o) {
        u16*   xT        = (u16*)((char*)d_ws + xT_off);
        uint2* sorted    = (uint2*)((char*)d_ws + sorted_off);
        u32*   ghist     = (u32*)((char*)d_ws + ghist_off);
        u32*   col_start = (u32*)((char*)d_ws + cs_off);
        u32*   cursor    = (u32*)((char*)d_ws + cur_off);
        float* outT      = (float*)((char*)d_ws + outT_off);

        // zero sorted (incl. pad slots) + ghist in one contiguous pass
        const size_t zero_bytes = (ghist_off - sorted_off) + UNITS * sizeof(u32);
        const int n4 = (int)((zero_bytes + 15) / 16);
        zero4_kernel<<<1024, 256, 0, stream>>>((uint4*)((char*)d_ws + sorted_off), n4);

        dim3 tb(64, 4);
        transpose_x_kernel<<<(nfeat + 63) / 64, tb, 0, stream>>>(x, xT, nfeat);
        hist_kernel<<<512, 256, 0, stream>>>(col_idx, ghist, nnz);
        scan_kernel<<<1, 1024, 0, stream>>>(ghist, col_start, cursor);
        reorder_kernel<<<(nnz + 2047) / 2048, 256, 0, stream>>>(
            row_idx, col_idx, w, cursor, sorted, nnz);
        gather_kernel<<<UNITS, 256, 0, stream>>>(xT, sorted, col_start, outT);
        transpose_out_kernel<<<UNITS / 64, tb, 0, stream>>>(outT, out);
    } else if (ws_size >= xT_bytes) {
        u16* xT = (u16*)d_ws;
        const int nOut4 = (out_size * 4 + 15) / 16;
        zero4_kernel<<<64, 256, 0, stream>>>((uint4*)out, nOut4);
        dim3 tb(64, 4);
        transpose_x_kernel<<<(nfeat + 63) / 64, tb, 0, stream>>>(x, xT, nfeat);
        scatter_fallback_kernel<<<256, 1024, 32 * UNITS * sizeof(float), stream>>>(
            xT, w, row_idx, col_idx, out, nnz);
    } else {
        const int nOut4 = (out_size * 4 + 15) / 16;
        zero4_kernel<<<64, 256, 0, stream>>>((uint4*)out, nOut4);
        fallback_kernel<<<2048, 256, 0, stream>>>(x, w, row_idx, col_idx, out, nnz, nfeat);
    }
}